// Round 2
// baseline (1090.868 us; speedup 1.0000x reference)
//
#include <hip/hip_runtime.h>
#include <math.h>

// Problem constants (fixed by the reference)
#define BS 4
#define DD 128
#define NN 65536
#define RR 8
#define NSTEPS 6
#define EPSV 1e-6f

// Big-kernel config: 256 threads, 1 n-column per thread -> 1024 blocks total
#define TPB 256
#define NTILE TPB              // 256 columns per block
#define NBLK (NN / NTILE)      // 256 blocks per batch
#define NWAVE (TPB / 64)       // 4 waves per block

#define SLOTB (BS * DD * RR)   // per-step bases / n2 slot stride (4096 floats)
#define SLOTC (BS * 64)        // per-step ctc slot stride (256 floats)

// ---------------------------------------------------------------------------
// 8-value transpose-reduce within each 8-lane group.
// Input: p[0..7] per lane. Output: sum over the lane's 8-lane group of
// p[lane & 7]  (i.e. lane l ends owning index r = l%8).
// ---------------------------------------------------------------------------
__device__ __forceinline__ float red8(const float p[8]) {
  const int l = threadIdx.x & 63;
  float t0 = p[0] + __shfl_xor(p[0], 1);
  float t1 = p[1] + __shfl_xor(p[1], 1);
  float t2 = p[2] + __shfl_xor(p[2], 1);
  float t3 = p[3] + __shfl_xor(p[3], 1);
  float t4 = p[4] + __shfl_xor(p[4], 1);
  float t5 = p[5] + __shfl_xor(p[5], 1);
  float t6 = p[6] + __shfl_xor(p[6], 1);
  float t7 = p[7] + __shfl_xor(p[7], 1);
  const bool s0 = (l & 1) != 0;
  float a0 = s0 ? t1 : t0;
  float a1 = s0 ? t3 : t2;
  float a2 = s0 ? t5 : t4;
  float a3 = s0 ? t7 : t6;
  float u0 = a0 + __shfl_xor(a0, 2);
  float u1 = a1 + __shfl_xor(a1, 2);
  float u2 = a2 + __shfl_xor(a2, 2);
  float u3 = a3 + __shfl_xor(a3, 2);
  const bool s1 = (l & 2) != 0;
  float c0 = s1 ? u1 : u0;
  float c1 = s1 ? u3 : u2;
  float w0 = c0 + __shfl_xor(c0, 4);
  float w1 = c1 + __shfl_xor(c1, 4);
  return (l & 4) ? w1 : w0;
}

// finish the reduction across the 8 groups of a 64-lane wave
__device__ __forceinline__ float wave_red(float v) {
  v += __shfl_xor(v, 8);
  v += __shfl_xor(v, 16);
  v += __shfl_xor(v, 32);
  return v;
}

__device__ __forceinline__ void load_row8(const float* __restrict__ p, float v[8]) {
  const float4* s4 = reinterpret_cast<const float4*>(p);
  float4 a = s4[0], b = s4[1];
  v[0] = a.x; v[1] = a.y; v[2] = a.z; v[3] = a.w;
  v[4] = b.x; v[5] = b.y; v[6] = b.z; v[7] = b.w;
}
__device__ __forceinline__ void store_row8(float* __restrict__ p, const float v[8]) {
  float4* s4 = reinterpret_cast<float4*>(p);
  s4[0] = make_float4(v[0], v[1], v[2], v[3]);
  s4[1] = make_float4(v[4], v[5], v[6], v[7]);
}

// ---------------------------------------------------------------------------
// k_init: normalize bases_init (L2 over D) -> bases slot0, compute BtB0,
// zero all per-step accumulator slots. grid = BS, TPB threads.
// ---------------------------------------------------------------------------
__global__ __launch_bounds__(TPB) void k_init(
    const float* __restrict__ bi, float* __restrict__ bases0,
    float* __restrict__ btb0, float* __restrict__ n2acc,
    float* __restrict__ ctcacc) {
  const int b = blockIdx.x;
  const int tid = threadIdx.x;
  __shared__ float nb[DD][RR];
  __shared__ float norms[RR];

  float v[RR];
  if (tid < DD) {
    load_row8(bi + ((size_t)b * DD + tid) * RR, v);
#pragma unroll
    for (int r = 0; r < RR; ++r) nb[tid][r] = v[r] * v[r];
  }
  __syncthreads();
  if (tid < RR) {
    float s = 0.f;
    for (int dd = 0; dd < DD; ++dd) s += nb[dd][tid];
    norms[tid] = fmaxf(sqrtf(s), 1e-12f);
  }
  __syncthreads();
  if (tid < DD) {
#pragma unroll
    for (int r = 0; r < RR; ++r) v[r] = v[r] / norms[r];
    store_row8(bases0 + ((size_t)b * DD + tid) * RR, v);
#pragma unroll
    for (int r = 0; r < RR; ++r) nb[tid][r] = v[r];
  }
  __syncthreads();
  if (tid < 64) {
    const int r = tid >> 3, s2 = tid & 7;
    float acc = 0.f;
    for (int dd = 0; dd < DD; ++dd) acc += nb[dd][r] * nb[dd][s2];
    btb0[b * 64 + tid] = acc;
  }
  // zero the 6 per-step accumulator slots for this batch
  for (int s = 0; s < NSTEPS; ++s) {
    for (int i = tid; i < DD * RR; i += TPB)
      n2acc[(size_t)s * SLOTB + b * DD * RR + i] = 0.f;
    if (tid < 64) ctcacc[(size_t)s * SLOTC + b * 64 + tid] = 0.f;
  }
}

// ---------------------------------------------------------------------------
// make_bases: build this step's bases (bl) + BtB (btbl) in LDS.
// FIRST: just load slot0 + btb0. Otherwise compute the multiplicative bases
// update from (bprev, n2prev, ctcprev); block x==0 persists it to bnext.
// All threads must call (contains __syncthreads).
// ---------------------------------------------------------------------------
template <bool FIRST>
__device__ __forceinline__ void make_bases(
    int b, int tid,
    const float* __restrict__ bprev, const float* __restrict__ btb0,
    const float* __restrict__ n2prev, const float* __restrict__ ctcprev,
    float* __restrict__ bnext, float (&bl)[DD][RR], float* btbl) {
  if (FIRST) {
    reinterpret_cast<float4*>(&bl[0][0])[tid] =
        reinterpret_cast<const float4*>(bprev + (size_t)b * DD * RR)[tid];
    if (tid < 64) btbl[tid] = btb0[b * 64 + tid];
    __syncthreads();
  } else {
    __shared__ float ctcs[64];
    if (tid < 64) ctcs[tid] = ctcprev[b * 64 + tid];
    float row[RR], n2r[RR];
    if (tid < DD) {
      load_row8(bprev + ((size_t)b * DD + tid) * RR, row);
      load_row8(n2prev + ((size_t)b * DD + tid) * RR, n2r);
    }
    __syncthreads();
    float nw[RR];
    if (tid < DD) {
#pragma unroll
      for (int r = 0; r < RR; ++r) {
        float den = EPSV;
#pragma unroll
        for (int s2 = 0; s2 < RR; ++s2) den = fmaf(row[s2], ctcs[s2 * 8 + r], den);
        nw[r] = row[r] * n2r[r] / den;
      }
#pragma unroll
      for (int r = 0; r < RR; ++r) bl[tid][r] = nw[r];
      if (bnext != nullptr && blockIdx.x == 0)
        store_row8(bnext + ((size_t)b * DD + tid) * RR, nw);
    }
    __syncthreads();
    if (tid < 64) {
      const int r = tid >> 3, s2 = tid & 7;
      float acc = 0.f;
      for (int dd = 0; dd < DD; ++dd) acc += bl[dd][r] * bl[dd][s2];
      btbl[tid] = acc;
    }
    __syncthreads();
  }
}

// ---------------------------------------------------------------------------
// k_step<FIRST>: bases prologue, then per 256-column tile:
//   s = xf^T bl;  coef_new = (FIRST ? softmax(s) : coef) * s / (coef@BtB+eps)
//   accumulate n2cur += xf*coef_new, ctccur += coef_new^T coef_new
// grid = (NBLK, BS), TPB threads.
// ---------------------------------------------------------------------------
template <bool FIRST>
__global__ __launch_bounds__(TPB) void k_step(
    const float* __restrict__ xf, float* __restrict__ coef,
    const float* __restrict__ bprev, const float* __restrict__ btb0,
    const float* __restrict__ n2prev, const float* __restrict__ ctcprev,
    float* __restrict__ bnext,
    float* __restrict__ n2cur, float* __restrict__ ctccur) {
  const int b = blockIdx.y;
  const int tid = threadIdx.x;
  const int lane = tid & 63;
  const int wv = tid >> 6;
  const size_t n0 = (size_t)blockIdx.x * NTILE + tid;
  const float* __restrict__ xb = xf + (size_t)b * DD * NN + n0;

  __shared__ float bl[DD][RR];          // 4 KB
  __shared__ float btbl[64];            // 256 B
  __shared__ float nlds[NWAVE][DD][RR]; // 16 KB
  __shared__ float ctcl[NWAVE][64];     // 1 KB

  make_bases<FIRST>(b, tid, bprev, btb0, n2prev, ctcprev, bnext, bl, btbl);

  // ---- pass 1: s = xf^T bl (8 outstanding loads via unroll)
  float s_[RR] = {0.f, 0.f, 0.f, 0.f, 0.f, 0.f, 0.f, 0.f};
#pragma unroll 8
  for (int d = 0; d < DD; ++d) {
    const float xv = xb[(size_t)d * NN];
    const float4 b03 = *reinterpret_cast<const float4*>(&bl[d][0]);
    const float4 b47 = *reinterpret_cast<const float4*>(&bl[d][4]);
    s_[0] = fmaf(xv, b03.x, s_[0]);
    s_[1] = fmaf(xv, b03.y, s_[1]);
    s_[2] = fmaf(xv, b03.z, s_[2]);
    s_[3] = fmaf(xv, b03.w, s_[3]);
    s_[4] = fmaf(xv, b47.x, s_[4]);
    s_[5] = fmaf(xv, b47.y, s_[5]);
    s_[6] = fmaf(xv, b47.z, s_[6]);
    s_[7] = fmaf(xv, b47.w, s_[7]);
  }

  // ---- coef update
  float* cp = coef + ((size_t)b * NN + n0) * RR;
  float c[RR];
  if (FIRST) {
    float m = s_[0];
#pragma unroll
    for (int r = 1; r < RR; ++r) m = fmaxf(m, s_[r]);
    float sum = 0.f;
#pragma unroll
    for (int r = 0; r < RR; ++r) {
      float e = __expf(s_[r] - m);
      c[r] = e;
      sum += e;
    }
#pragma unroll
    for (int r = 0; r < RR; ++r) c[r] = c[r] / sum;
  } else {
    load_row8(cp, c);
  }
  {
    float den[RR];
#pragma unroll
    for (int r = 0; r < RR; ++r) {
      float dv = EPSV;
#pragma unroll
      for (int t2 = 0; t2 < RR; ++t2) dv = fmaf(c[t2], btbl[t2 * 8 + r], dv);
      den[r] = dv;
    }
#pragma unroll
    for (int r = 0; r < RR; ++r) c[r] = c[r] * s_[r] / den[r];
  }
  store_row8(cp, c);

  // ---- pass 2: n2[d][r] += sum_n x[d][n]*c[n][r]  (x re-read, L3-hot)
#pragma unroll 4
  for (int d = 0; d < DD; ++d) {
    const float xv = xb[(size_t)d * NN];
    float p[RR];
#pragma unroll
    for (int r = 0; r < RR; ++r) p[r] = xv * c[r];
    float v = wave_red(red8(p));
    if (lane < RR) nlds[wv][d][lane] = v;
  }
  // ---- CtC (once per thread)
#pragma unroll
  for (int r = 0; r < RR; ++r) {
    float p2[RR];
#pragma unroll
    for (int s2 = 0; s2 < RR; ++s2) p2[s2] = c[r] * c[s2];
    float v = wave_red(red8(p2));
    if (lane < RR) ctcl[wv][r * 8 + lane] = v;
  }
  __syncthreads();

  const float* nf = &nlds[0][0][0];
  for (int i = tid; i < DD * RR; i += TPB) {
    float acc = nf[i] + nf[DD * RR + i] + nf[2 * DD * RR + i] + nf[3 * DD * RR + i];
    atomicAdd(&n2cur[b * DD * RR + i], acc);
  }
  if (tid < 64) {
    float acc = ctcl[0][tid] + ctcl[1][tid] + ctcl[2][tid] + ctcl[3][tid];
    atomicAdd(&ctccur[b * 64 + tid], acc);
  }
}

// ---------------------------------------------------------------------------
// k_final: bases_6 prologue + last coef update (compute_coef) fused with
// reconstruction out = bl @ coef^T. grid = (NBLK, BS), TPB threads.
// ---------------------------------------------------------------------------
__global__ __launch_bounds__(TPB) void k_final(
    const float* __restrict__ xf, const float* __restrict__ coef,
    const float* __restrict__ bprev, const float* __restrict__ n2prev,
    const float* __restrict__ ctcprev, float* __restrict__ out) {
  const int b = blockIdx.y;
  const int tid = threadIdx.x;
  const size_t n0 = (size_t)blockIdx.x * NTILE + tid;
  const float* __restrict__ xb = xf + (size_t)b * DD * NN + n0;

  __shared__ float bl[DD][RR];
  __shared__ float btbl[64];

  make_bases<false>(b, tid, bprev, nullptr, n2prev, ctcprev, nullptr, bl, btbl);

  float s_[RR] = {0.f, 0.f, 0.f, 0.f, 0.f, 0.f, 0.f, 0.f};
#pragma unroll 8
  for (int d = 0; d < DD; ++d) {
    const float xv = xb[(size_t)d * NN];
    const float4 b03 = *reinterpret_cast<const float4*>(&bl[d][0]);
    const float4 b47 = *reinterpret_cast<const float4*>(&bl[d][4]);
    s_[0] = fmaf(xv, b03.x, s_[0]);
    s_[1] = fmaf(xv, b03.y, s_[1]);
    s_[2] = fmaf(xv, b03.z, s_[2]);
    s_[3] = fmaf(xv, b03.w, s_[3]);
    s_[4] = fmaf(xv, b47.x, s_[4]);
    s_[5] = fmaf(xv, b47.y, s_[5]);
    s_[6] = fmaf(xv, b47.z, s_[6]);
    s_[7] = fmaf(xv, b47.w, s_[7]);
  }

  float c[RR];
  load_row8(coef + ((size_t)b * NN + n0) * RR, c);
  {
    float den[RR];
#pragma unroll
    for (int r = 0; r < RR; ++r) {
      float dv = EPSV;
#pragma unroll
      for (int t2 = 0; t2 < RR; ++t2) dv = fmaf(c[t2], btbl[t2 * 8 + r], dv);
      den[r] = dv;
    }
#pragma unroll
    for (int r = 0; r < RR; ++r) c[r] = c[r] * s_[r] / den[r];
  }

  float* ob = out + (size_t)b * DD * NN + n0;
#pragma unroll 4
  for (int d = 0; d < DD; ++d) {
    const float4 b03 = *reinterpret_cast<const float4*>(&bl[d][0]);
    const float4 b47 = *reinterpret_cast<const float4*>(&bl[d][4]);
    float o = b03.x * c[0];
    o = fmaf(b03.y, c[1], o);
    o = fmaf(b03.z, c[2], o);
    o = fmaf(b03.w, c[3], o);
    o = fmaf(b47.x, c[4], o);
    o = fmaf(b47.y, c[5], o);
    o = fmaf(b47.z, c[6], o);
    o = fmaf(b47.w, c[7], o);
    ob[(size_t)d * NN] = o;
  }
}

// ---------------------------------------------------------------------------
extern "C" void kernel_launch(void* const* d_in, const int* in_sizes, int n_in,
                              void* d_out, int out_size, void* d_ws, size_t ws_size,
                              hipStream_t stream) {
  const float* x = (const float*)d_in[0];   // [BS, DD, NN] fp32
  const float* bi = (const float*)d_in[1];  // [BS, DD, RR] fp32
  float* out = (float*)d_out;               // [BS, DD, NN] fp32

  // workspace (floats): coef | bases_store[6] | btb0 | n2acc[6] | ctcacc[6]
  float* coef = (float*)d_ws;                          // BS*NN*RR
  float* bases_store = coef + (size_t)BS * NN * RR;    // 6 * SLOTB
  float* btb0 = bases_store + (size_t)6 * SLOTB;       // BS*64
  float* n2acc = btb0 + (size_t)BS * 64;               // 6 * SLOTB
  float* ctcacc = n2acc + (size_t)6 * SLOTB;           // 6 * SLOTC

  dim3 gbig(NBLK, BS);

  k_init<<<dim3(BS), TPB, 0, stream>>>(bi, bases_store, btb0, n2acc, ctcacc);

  // step 0: softmax init fused with first coef update; uses bases slot 0
  k_step<true><<<gbig, TPB, 0, stream>>>(x, coef, bases_store, btb0, nullptr,
                                         nullptr, nullptr, n2acc, ctcacc);
  // steps 1..5: bases prologue folded in; block x==0 persists bases slot s
  for (int s = 1; s < NSTEPS; ++s) {
    k_step<false><<<gbig, TPB, 0, stream>>>(
        x, coef, bases_store + (size_t)(s - 1) * SLOTB, nullptr,
        n2acc + (size_t)(s - 1) * SLOTB, ctcacc + (size_t)(s - 1) * SLOTC,
        bases_store + (size_t)s * SLOTB, n2acc + (size_t)s * SLOTB,
        ctcacc + (size_t)s * SLOTC);
  }

  // final: bases_6 prologue + compute_coef + reconstruction
  k_final<<<gbig, TPB, 0, stream>>>(
      x, coef, bases_store + (size_t)5 * SLOTB, n2acc + (size_t)5 * SLOTB,
      ctcacc + (size_t)5 * SLOTC, out);
}